// Round 5
// baseline (103.445 us; speedup 1.0000x reference)
//
#include <hip/hip_runtime.h>
#include <math.h>

// SpeciesDetector: pairwise Gaussian-transport KL + sigmoid gate.
// N=64, M=8, G=64, D=4.
//
// Factored KL (R2):
//   Sigma_bt^-1 = Oa^-T (Ob^T Sb^-1 Ob) Oa^-1 = Oa^-T Q_b Oa^-1
//   mahal = u^T Q_b u,  u = Oa^-1 mu_a - Ob^-1 mu_b
//   tr    = trace(Q_b P_a),  P_a = Oa^-1 Sa Oa^-T   (both symmetric, 10 coeffs)
//   kl    = 0.5*(tr + mahal - 4 + lb - la),
//   lb = ln det Sb - 2 ln|det Ob|,  la = ln det Sa - 2 ln|det Oa|
//
// R5: a-side setup moved OUT of the hot kernel (R4 showed setup VALU is the
// expensive half). One fused precompute kernel packs, plane-major float4:
//   b-side (32768): {Q00,2Q01,2Q02,2Q03} {Q11,2Q12,2Q13,Q22} {2Q23,Q33,lb,0} {v}
//   a-side (262144): {Pf0..3} {Pf4..7} {Pf8,Pf9,la,chi} {w}
// Main kernel = pure streaming KL: 4 a-float4 + 8x(4 b-float4 + ~48 VALU) + 8
// stores, everything coalesced, zero inverses/logs in the hot loop.

namespace {

constexpr int kN = 64;
constexpr int kM = 8;
constexpr int kG = 64;
constexpr int kGH = kG * kG;        // 4096
constexpr int kMB = kM * kGH;       // 32768 b-side entries
constexpr int kNA = kN * kGH;       // 262144 a-side entries
constexpr float kInvTau = 1.0f / 5.0f;

__device__ __forceinline__ void load16(const float* __restrict__ p, int idx,
                                       float* __restrict__ o) {
    const float4* p4 = reinterpret_cast<const float4*>(p);
#pragma unroll
    for (int k = 0; k < 4; ++k) {
        float4 v = p4[idx * 4 + k];
        o[4 * k + 0] = v.x;
        o[4 * k + 1] = v.y;
        o[4 * k + 2] = v.z;
        o[4 * k + 3] = v.w;
    }
}

__device__ __forceinline__ float det4(const float* __restrict__ m) {
    float s0 = m[0] * m[5] - m[1] * m[4];
    float s1 = m[0] * m[6] - m[2] * m[4];
    float s2 = m[0] * m[7] - m[3] * m[4];
    float s3 = m[1] * m[6] - m[2] * m[5];
    float s4 = m[1] * m[7] - m[3] * m[5];
    float s5 = m[2] * m[7] - m[3] * m[6];
    float c5 = m[10] * m[15] - m[11] * m[14];
    float c4 = m[9] * m[15] - m[11] * m[13];
    float c3 = m[9] * m[14] - m[10] * m[13];
    float c2 = m[8] * m[15] - m[11] * m[12];
    float c1 = m[8] * m[14] - m[10] * m[12];
    float c0 = m[8] * m[13] - m[9] * m[12];
    return s0 * c5 - s1 * c4 + s2 * c3 + s3 * c2 - s4 * c1 + s5 * c0;
}

// Adjugate inverse of row-major 4x4; returns det. rcp is HW approx (~1 ulp).
__device__ __forceinline__ float inv4(const float* __restrict__ m,
                                      float* __restrict__ inv) {
    float s0 = m[0] * m[5] - m[1] * m[4];
    float s1 = m[0] * m[6] - m[2] * m[4];
    float s2 = m[0] * m[7] - m[3] * m[4];
    float s3 = m[1] * m[6] - m[2] * m[5];
    float s4 = m[1] * m[7] - m[3] * m[5];
    float s5 = m[2] * m[7] - m[3] * m[6];
    float c5 = m[10] * m[15] - m[11] * m[14];
    float c4 = m[9] * m[15] - m[11] * m[13];
    float c3 = m[9] * m[14] - m[10] * m[13];
    float c2 = m[8] * m[15] - m[11] * m[12];
    float c1 = m[8] * m[14] - m[10] * m[12];
    float c0 = m[8] * m[13] - m[9] * m[12];
    float det = s0 * c5 - s1 * c4 + s2 * c3 + s3 * c2 - s4 * c1 + s5 * c0;
    float r = __builtin_amdgcn_rcpf(det);
    inv[0]  = ( m[5]  * c5 - m[6]  * c4 + m[7]  * c3) * r;
    inv[1]  = (-m[1]  * c5 + m[2]  * c4 - m[3]  * c3) * r;
    inv[2]  = ( m[13] * s5 - m[14] * s4 + m[15] * s3) * r;
    inv[3]  = (-m[9]  * s5 + m[10] * s4 - m[11] * s3) * r;
    inv[4]  = (-m[4]  * c5 + m[6]  * c2 - m[7]  * c1) * r;
    inv[5]  = ( m[0]  * c5 - m[2]  * c2 + m[3]  * c1) * r;
    inv[6]  = (-m[12] * s5 + m[14] * s2 - m[15] * s1) * r;
    inv[7]  = ( m[8]  * s5 - m[10] * s2 + m[11] * s1) * r;
    inv[8]  = ( m[4]  * c4 - m[5]  * c2 + m[7]  * c0) * r;
    inv[9]  = (-m[0]  * c4 + m[1]  * c2 - m[3]  * c0) * r;
    inv[10] = ( m[12] * s4 - m[13] * s2 + m[15] * s0) * r;
    inv[11] = (-m[8]  * s4 + m[9]  * s2 - m[11] * s0) * r;
    inv[12] = (-m[4]  * c3 + m[5]  * c1 - m[6]  * c0) * r;
    inv[13] = ( m[0]  * c3 - m[1]  * c1 + m[2]  * c0) * r;
    inv[14] = (-m[12] * s3 + m[13] * s1 - m[14] * s0) * r;
    inv[15] = ( m[8]  * s3 - m[9]  * s1 + m[10] * s0) * r;
    return det;
}

// Fused precompute. Blocks [0,128): b-side entry idx = blk*256+tid.
// Blocks [128,1152): a-side entry t = (blk-128)*256+tid. Branch is
// block-uniform -> no divergence.
__global__ __launch_bounds__(256) void precompute_kernel(
    const float* __restrict__ mu_a,
    const float* __restrict__ sigma_a,
    const float* __restrict__ omega_a,
    const float* __restrict__ chi,
    const float* __restrict__ mu_b,
    const float* __restrict__ sigma_b,
    const float* __restrict__ omega_b,
    float4* __restrict__ ws)
{
    const int blk = blockIdx.x;
    if (blk < kMB / 256) {
        // ---------------- b-side ----------------
        const int idx = blk * 256 + threadIdx.x;  // m*4096 + gh
        float Sb[16], Ob[16];
        load16(sigma_b, idx, Sb);
        load16(omega_b, idx, Ob);
        float SbI[16], ObI[16];
        const float detSb = inv4(Sb, SbI);
        const float detOb = inv4(Ob, ObI);
        const float4 mb4 = reinterpret_cast<const float4*>(mu_b)[idx];
        const float mb[4] = {mb4.x, mb4.y, mb4.z, mb4.w};

        // R = Sb^-1 * Ob ; Q = Ob^T R (sym, off-diag doubled)
        float R[16];
#pragma unroll
        for (int i = 0; i < 4; ++i)
#pragma unroll
            for (int k = 0; k < 4; ++k)
                R[i * 4 + k] = SbI[i * 4 + 0] * Ob[0 * 4 + k]
                             + SbI[i * 4 + 1] * Ob[1 * 4 + k]
                             + SbI[i * 4 + 2] * Ob[2 * 4 + k]
                             + SbI[i * 4 + 3] * Ob[3 * 4 + k];
        float Qf[10];
        int pi = 0;
#pragma unroll
        for (int i = 0; i < 4; ++i)
#pragma unroll
            for (int k = 0; k < 4; ++k) {
                if (k < i) continue;
                float q = Ob[0 * 4 + i] * R[0 * 4 + k]
                        + Ob[1 * 4 + i] * R[1 * 4 + k]
                        + Ob[2 * 4 + i] * R[2 * 4 + k]
                        + Ob[3 * 4 + i] * R[3 * 4 + k];
                Qf[pi++] = (i == k) ? q : 2.0f * q;
            }
        float v[4];
#pragma unroll
        for (int i = 0; i < 4; ++i)
            v[i] = ObI[i * 4 + 0] * mb[0] + ObI[i * 4 + 1] * mb[1]
                 + ObI[i * 4 + 2] * mb[2] + ObI[i * 4 + 3] * mb[3];

        const float lb = __logf(fabsf(detSb)) - 2.0f * __logf(fabsf(detOb));

        ws[0 * kMB + idx] = make_float4(Qf[0], Qf[1], Qf[2], Qf[3]);
        ws[1 * kMB + idx] = make_float4(Qf[4], Qf[5], Qf[6], Qf[7]);
        ws[2 * kMB + idx] = make_float4(Qf[8], Qf[9], lb, 0.0f);
        ws[3 * kMB + idx] = make_float4(v[0], v[1], v[2], v[3]);
    } else {
        // ---------------- a-side ----------------
        const int t = (blk - kMB / 256) * 256 + threadIdx.x;  // n*4096 + gh
        float Sa[16], Oa[16], OaI[16];
        load16(sigma_a, t, Sa);
        load16(omega_a, t, Oa);
        const float detOa = inv4(Oa, OaI);
        const float detSa = det4(Sa);
        const float la = __logf(fabsf(detSa)) - 2.0f * __logf(fabsf(detOa));
        const float4 ma4 = reinterpret_cast<const float4*>(mu_a)[t];
        const float ma[4] = {ma4.x, ma4.y, ma4.z, ma4.w};
        const float xchi = chi[t];

        // w = Oa^-1 mu_a
        float w[4];
#pragma unroll
        for (int i = 0; i < 4; ++i)
            w[i] = OaI[i * 4 + 0] * ma[0] + OaI[i * 4 + 1] * ma[1]
                 + OaI[i * 4 + 2] * ma[2] + OaI[i * 4 + 3] * ma[3];

        // P = Oa^-1 Sa Oa^-T (symmetric, 10 coeffs)
        float Mt[16];
#pragma unroll
        for (int i = 0; i < 4; ++i)
#pragma unroll
            for (int k = 0; k < 4; ++k)
                Mt[i * 4 + k] = OaI[i * 4 + 0] * Sa[0 * 4 + k]
                              + OaI[i * 4 + 1] * Sa[1 * 4 + k]
                              + OaI[i * 4 + 2] * Sa[2 * 4 + k]
                              + OaI[i * 4 + 3] * Sa[3 * 4 + k];
        float Pf[10];
        int pi = 0;
#pragma unroll
        for (int i = 0; i < 4; ++i)
#pragma unroll
            for (int k = 0; k < 4; ++k) {
                if (k < i) continue;
                Pf[pi++] = Mt[i * 4 + 0] * OaI[k * 4 + 0]
                         + Mt[i * 4 + 1] * OaI[k * 4 + 1]
                         + Mt[i * 4 + 2] * OaI[k * 4 + 2]
                         + Mt[i * 4 + 3] * OaI[k * 4 + 3];
            }

        float4* wsA = ws + 4 * kMB;
        wsA[0 * kNA + t] = make_float4(Pf[0], Pf[1], Pf[2], Pf[3]);
        wsA[1 * kNA + t] = make_float4(Pf[4], Pf[5], Pf[6], Pf[7]);
        wsA[2 * kNA + t] = make_float4(Pf[8], Pf[9], la, xchi);
        wsA[3 * kNA + t] = make_float4(w[0], w[1], w[2], w[3]);
    }
}

// Pure streaming KL: one thread per (n,gh), all 8 m. Everything coalesced.
__global__ __launch_bounds__(256) void species_kernel(
    const float4* __restrict__ ws,
    float* __restrict__ out)           // (N,M,G,G)
{
    const int t = blockIdx.x * blockDim.x + threadIdx.x;  // n*4096 + gh
    const int gh = t & (kGH - 1);
    const int n = t >> 12;

    const float4* __restrict__ wsA = ws + 4 * kMB;
    const float4 a0 = wsA[0 * kNA + t];
    const float4 a1 = wsA[1 * kNA + t];
    const float4 a2 = wsA[2 * kNA + t];
    const float4 a3 = wsA[3 * kNA + t];
    const float la = a2.z;
    const float xchi = a2.w;

#pragma unroll
    for (int m = 0; m < kM; ++m) {
        const int bb = m * kGH + gh;
        const float4 q0 = ws[0 * kMB + bb];
        const float4 q1 = ws[1 * kMB + bb];
        const float4 q2 = ws[2 * kMB + bb];
        const float4 q3 = ws[3 * kMB + bb];

        const float u0 = a3.x - q3.x;
        const float u1 = a3.y - q3.y;
        const float u2 = a3.z - q3.z;
        const float u3 = a3.w - q3.w;

        float tr = q0.x * a0.x + q0.y * a0.y + q0.z * a0.z + q0.w * a0.w
                 + q1.x * a1.x + q1.y * a1.y + q1.z * a1.z + q1.w * a1.w
                 + q2.x * a2.x + q2.y * a2.y;
        float mah = q0.x * (u0 * u0) + q0.y * (u0 * u1) + q0.z * (u0 * u2)
                  + q0.w * (u0 * u3) + q1.x * (u1 * u1) + q1.y * (u1 * u2)
                  + q1.z * (u1 * u3) + q1.w * (u2 * u2) + q2.x * (u2 * u3)
                  + q2.y * (u3 * u3);

        const float kl = 0.5f * (tr + mah - 4.0f + q2.z - la);
        // sigmoid(-kl/tau)*chi; e->inf => rcp(inf)=0 (correct limit)
        const float e = __expf(kl * kInvTau);
        const float s = xchi * __builtin_amdgcn_rcpf(1.0f + e);
        out[(n * kM + m) * kGH + gh] = s;
    }
}

}  // namespace

extern "C" void kernel_launch(void* const* d_in, const int* in_sizes, int n_in,
                              void* d_out, int out_size, void* d_ws, size_t ws_size,
                              hipStream_t stream) {
    const float* mu_a    = (const float*)d_in[0];
    const float* sigma_a = (const float*)d_in[1];
    const float* omega_a = (const float*)d_in[2];
    const float* mu_b    = (const float*)d_in[3];
    const float* sigma_b = (const float*)d_in[4];
    const float* omega_b = (const float*)d_in[5];
    const float* chi     = (const float*)d_in[6];
    float* out = (float*)d_out;
    float4* ws = (float4*)d_ws;  // uses 4*(32768+262144)*16 B = 18 MiB

    const int nBlocksB = kMB / 256;            // 128
    const int nBlocksA = kNA / 256;            // 1024
    precompute_kernel<<<nBlocksB + nBlocksA, 256, 0, stream>>>(
        mu_a, sigma_a, omega_a, chi, mu_b, sigma_b, omega_b, ws);

    species_kernel<<<kNA / 256, 256, 0, stream>>>(ws, out);
}

// Round 6
// 98.113 us; speedup vs baseline: 1.0543x; 1.0543x over previous
//
#include <hip/hip_runtime.h>
#include <math.h>

// SpeciesDetector: pairwise Gaussian-transport KL + sigmoid gate.
// N=64, M=8, G=64, D=4.
//
// Factored KL (R2):
//   Sigma_bt^-1 = Oa^-T (Ob^T Sb^-1 Ob) Oa^-1 = Oa^-T Q_b Oa^-1
//   mahal = u^T Q_b u,  u = Oa^-1 mu_a - Ob^-1 mu_b
//   tr    = trace(Q_b P_a),  P_a = Oa^-1 Sa Oa^-T   (both symmetric, 10 coeffs)
//   kl    = 0.5*(tr + mahal - 4 + lb - la)
// ws (R3): b-side pack plane-major float4 (4 x 32768), fully coalesced,
// 2 MiB -> L2-resident, reused 64x.
//
// R6 = R3 + block-cooperative LDS staging of Sa/Oa (the good half of R4,
// WITHOUT the m-split that quadrupled setup VALU):
//   - 256-thread block covers 256 consecutive (n,gh).
//   - each thread loads 4+4 consecutive float4s (coalesced 1KB/wave/inst)
//     into stride-20 padded LDS (16B-aligned quarters; R4 measured 0 bank
//     conflicts with this pattern), one barrier, then b128 LDS reads.
//   - fixes the lane-stride-64B load16 pattern (4x L1 line-request
//     amplification on the 33 MB a-side stream).
//   - setup (inv4/logs/P) stays 1x per (n,gh) -- R4/R5 showed duplicating
//     or relocating it loses more than it gains.

namespace {

constexpr int kN = 64;
constexpr int kM = 8;
constexpr int kG = 64;
constexpr int kGH = kG * kG;        // 4096
constexpr int kMB = kM * kGH;       // 32768 b-side entries
constexpr int kNA = kN * kGH;       // 262144 a-side entries
constexpr float kInvTau = 1.0f / 5.0f;
constexpr int kPad = 20;            // LDS row stride in floats (16B-aligned)

__device__ __forceinline__ void load16(const float* __restrict__ p, int idx,
                                       float* __restrict__ o) {
    const float4* p4 = reinterpret_cast<const float4*>(p);
#pragma unroll
    for (int k = 0; k < 4; ++k) {
        float4 v = p4[idx * 4 + k];
        o[4 * k + 0] = v.x;
        o[4 * k + 1] = v.y;
        o[4 * k + 2] = v.z;
        o[4 * k + 3] = v.w;
    }
}

__device__ __forceinline__ float det4(const float* __restrict__ m) {
    float s0 = m[0] * m[5] - m[1] * m[4];
    float s1 = m[0] * m[6] - m[2] * m[4];
    float s2 = m[0] * m[7] - m[3] * m[4];
    float s3 = m[1] * m[6] - m[2] * m[5];
    float s4 = m[1] * m[7] - m[3] * m[5];
    float s5 = m[2] * m[7] - m[3] * m[6];
    float c5 = m[10] * m[15] - m[11] * m[14];
    float c4 = m[9] * m[15] - m[11] * m[13];
    float c3 = m[9] * m[14] - m[10] * m[13];
    float c2 = m[8] * m[15] - m[11] * m[12];
    float c1 = m[8] * m[14] - m[10] * m[12];
    float c0 = m[8] * m[13] - m[9] * m[12];
    return s0 * c5 - s1 * c4 + s2 * c3 + s3 * c2 - s4 * c1 + s5 * c0;
}

// Adjugate inverse of row-major 4x4; returns det. rcp is HW approx (~1 ulp).
__device__ __forceinline__ float inv4(const float* __restrict__ m,
                                      float* __restrict__ inv) {
    float s0 = m[0] * m[5] - m[1] * m[4];
    float s1 = m[0] * m[6] - m[2] * m[4];
    float s2 = m[0] * m[7] - m[3] * m[4];
    float s3 = m[1] * m[6] - m[2] * m[5];
    float s4 = m[1] * m[7] - m[3] * m[5];
    float s5 = m[2] * m[7] - m[3] * m[6];
    float c5 = m[10] * m[15] - m[11] * m[14];
    float c4 = m[9] * m[15] - m[11] * m[13];
    float c3 = m[9] * m[14] - m[10] * m[13];
    float c2 = m[8] * m[15] - m[11] * m[12];
    float c1 = m[8] * m[14] - m[10] * m[12];
    float c0 = m[8] * m[13] - m[9] * m[12];
    float det = s0 * c5 - s1 * c4 + s2 * c3 + s3 * c2 - s4 * c1 + s5 * c0;
    float r = __builtin_amdgcn_rcpf(det);
    inv[0]  = ( m[5]  * c5 - m[6]  * c4 + m[7]  * c3) * r;
    inv[1]  = (-m[1]  * c5 + m[2]  * c4 - m[3]  * c3) * r;
    inv[2]  = ( m[13] * s5 - m[14] * s4 + m[15] * s3) * r;
    inv[3]  = (-m[9]  * s5 + m[10] * s4 - m[11] * s3) * r;
    inv[4]  = (-m[4]  * c5 + m[6]  * c2 - m[7]  * c1) * r;
    inv[5]  = ( m[0]  * c5 - m[2]  * c2 + m[3]  * c1) * r;
    inv[6]  = (-m[12] * s5 + m[14] * s2 - m[15] * s1) * r;
    inv[7]  = ( m[8]  * s5 - m[10] * s2 + m[11] * s1) * r;
    inv[8]  = ( m[4]  * c4 - m[5]  * c2 + m[7]  * c0) * r;
    inv[9]  = (-m[0]  * c4 + m[1]  * c2 - m[3]  * c0) * r;
    inv[10] = ( m[12] * s4 - m[13] * s2 + m[15] * s0) * r;
    inv[11] = (-m[8]  * s4 + m[9]  * s2 - m[11] * s0) * r;
    inv[12] = (-m[4]  * c3 + m[5]  * c1 - m[6]  * c0) * r;
    inv[13] = ( m[0]  * c3 - m[1]  * c1 + m[2]  * c0) * r;
    inv[14] = (-m[12] * s3 + m[13] * s1 - m[14] * s0) * r;
    inv[15] = ( m[8]  * s3 - m[9]  * s1 + m[10] * s0) * r;
    return det;
}

// Per-(m,gh): Q_b = Ob^T Sb^-1 Ob (sym, off-diag pre-doubled), v = Ob^-1 mu_b,
// lb = ln det Sb - 2 ln|det Ob|. Plane-major float4.
__global__ __launch_bounds__(256) void precompute_b_kernel(
    const float* __restrict__ mu_b,
    const float* __restrict__ sigma_b,
    const float* __restrict__ omega_b,
    float4* __restrict__ ws)
{
    const int idx = blockIdx.x * blockDim.x + threadIdx.x;  // m*4096 + gh
    float Sb[16], Ob[16];
    load16(sigma_b, idx, Sb);
    load16(omega_b, idx, Ob);
    float SbI[16], ObI[16];
    const float detSb = inv4(Sb, SbI);
    const float detOb = inv4(Ob, ObI);
    const float4 mb4 = reinterpret_cast<const float4*>(mu_b)[idx];
    const float mb[4] = {mb4.x, mb4.y, mb4.z, mb4.w};

    float R[16];
#pragma unroll
    for (int i = 0; i < 4; ++i)
#pragma unroll
        for (int k = 0; k < 4; ++k)
            R[i * 4 + k] = SbI[i * 4 + 0] * Ob[0 * 4 + k]
                         + SbI[i * 4 + 1] * Ob[1 * 4 + k]
                         + SbI[i * 4 + 2] * Ob[2 * 4 + k]
                         + SbI[i * 4 + 3] * Ob[3 * 4 + k];
    float Qf[10];
    int pi = 0;
#pragma unroll
    for (int i = 0; i < 4; ++i)
#pragma unroll
        for (int k = 0; k < 4; ++k) {
            if (k < i) continue;
            float q = Ob[0 * 4 + i] * R[0 * 4 + k]
                    + Ob[1 * 4 + i] * R[1 * 4 + k]
                    + Ob[2 * 4 + i] * R[2 * 4 + k]
                    + Ob[3 * 4 + i] * R[3 * 4 + k];
            Qf[pi++] = (i == k) ? q : 2.0f * q;
        }
    float v[4];
#pragma unroll
    for (int i = 0; i < 4; ++i)
        v[i] = ObI[i * 4 + 0] * mb[0] + ObI[i * 4 + 1] * mb[1]
             + ObI[i * 4 + 2] * mb[2] + ObI[i * 4 + 3] * mb[3];

    const float lb = __logf(fabsf(detSb)) - 2.0f * __logf(fabsf(detOb));

    ws[0 * kMB + idx] = make_float4(Qf[0], Qf[1], Qf[2], Qf[3]);
    ws[1 * kMB + idx] = make_float4(Qf[4], Qf[5], Qf[6], Qf[7]);
    ws[2 * kMB + idx] = make_float4(Qf[8], Qf[9], lb, 0.0f);
    ws[3 * kMB + idx] = make_float4(v[0], v[1], v[2], v[3]);
}

// One thread per (n,gh), all 8 m. Sa/Oa staged through LDS for coalescing.
__global__ __launch_bounds__(256) void species_kernel(
    const float* __restrict__ mu_a,    // (N,G,G,D)
    const float* __restrict__ sigma_a, // (N,G,G,D,D)
    const float* __restrict__ omega_a, // (N,G,G,D,D)
    const float* __restrict__ chi,     // (N,G,G)
    const float4* __restrict__ ws,     // plane-major b-side, 4 x 32768 float4
    float* __restrict__ out)           // (N,M,G,G)
{
    __shared__ float sS[256 * kPad];   // 20 KB
    __shared__ float sO[256 * kPad];   // 20 KB

    const int tid = threadIdx.x;        // 0..255
    const int t0 = blockIdx.x * 256;    // 256-aligned: block never crosses n
    const int t = t0 + tid;
    const int gh = t & (kGH - 1);
    const int n = t >> 12;

    // ---- cooperative coalesced staging: 1024 float4 per array per block ----
    {
        const float4* gs = reinterpret_cast<const float4*>(sigma_a) + (size_t)t0 * 4;
        const float4* go = reinterpret_cast<const float4*>(omega_a) + (size_t)t0 * 4;
#pragma unroll
        for (int j = 0; j < 4; ++j) {
            const int f = tid + 256 * j;        // consecutive across lanes
            const int r = f >> 2;               // matrix row in block
            const int q = (f & 3) * 4;          // quarter offset (16B-aligned)
            *reinterpret_cast<float4*>(&sS[r * kPad + q]) = gs[f];
            *reinterpret_cast<float4*>(&sO[r * kPad + q]) = go[f];
        }
    }
    __syncthreads();

    // ---- per-thread a-side setup (once; b128 LDS reads) ----
    float Sa[16], Oa[16], OaI[16];
#pragma unroll
    for (int j = 0; j < 16; ++j) {
        Sa[j] = sS[tid * kPad + j];
        Oa[j] = sO[tid * kPad + j];
    }
    const float detOa = inv4(Oa, OaI);
    const float detSa = det4(Sa);
    const float la = __logf(fabsf(detSa)) - 2.0f * __logf(fabsf(detOa));
    const float4 ma4 = reinterpret_cast<const float4*>(mu_a)[t];
    const float ma[4] = {ma4.x, ma4.y, ma4.z, ma4.w};
    const float xchi = chi[t];

    // w = Oa^-1 mu_a
    float w[4];
#pragma unroll
    for (int i = 0; i < 4; ++i)
        w[i] = OaI[i * 4 + 0] * ma[0] + OaI[i * 4 + 1] * ma[1]
             + OaI[i * 4 + 2] * ma[2] + OaI[i * 4 + 3] * ma[3];

    // P = Oa^-1 Sa Oa^-T (symmetric, 10 coeffs)
    float Mt[16];
#pragma unroll
    for (int i = 0; i < 4; ++i)
#pragma unroll
        for (int k = 0; k < 4; ++k)
            Mt[i * 4 + k] = OaI[i * 4 + 0] * Sa[0 * 4 + k]
                          + OaI[i * 4 + 1] * Sa[1 * 4 + k]
                          + OaI[i * 4 + 2] * Sa[2 * 4 + k]
                          + OaI[i * 4 + 3] * Sa[3 * 4 + k];
    float Pf[10];
    {
        int pi = 0;
#pragma unroll
        for (int i = 0; i < 4; ++i)
#pragma unroll
            for (int k = 0; k < 4; ++k) {
                if (k < i) continue;
                Pf[pi++] = Mt[i * 4 + 0] * OaI[k * 4 + 0]
                         + Mt[i * 4 + 1] * OaI[k * 4 + 1]
                         + Mt[i * 4 + 2] * OaI[k * 4 + 2]
                         + Mt[i * 4 + 3] * OaI[k * 4 + 3];
            }
    }

    // ---- m-loop: 4 coalesced float4 loads (L2-hit) + ~48 VALU per m ----
#pragma unroll
    for (int m = 0; m < kM; ++m) {
        const int bb = m * kGH + gh;
        const float4 q0 = ws[0 * kMB + bb];
        const float4 q1 = ws[1 * kMB + bb];
        const float4 q2 = ws[2 * kMB + bb];
        const float4 q3 = ws[3 * kMB + bb];

        const float u0 = w[0] - q3.x;
        const float u1 = w[1] - q3.y;
        const float u2 = w[2] - q3.z;
        const float u3 = w[3] - q3.w;

        float tr = q0.x * Pf[0] + q0.y * Pf[1] + q0.z * Pf[2] + q0.w * Pf[3]
                 + q1.x * Pf[4] + q1.y * Pf[5] + q1.z * Pf[6] + q1.w * Pf[7]
                 + q2.x * Pf[8] + q2.y * Pf[9];
        float mah = q0.x * (u0 * u0) + q0.y * (u0 * u1) + q0.z * (u0 * u2)
                  + q0.w * (u0 * u3) + q1.x * (u1 * u1) + q1.y * (u1 * u2)
                  + q1.z * (u1 * u3) + q1.w * (u2 * u2) + q2.x * (u2 * u3)
                  + q2.y * (u3 * u3);

        const float kl = 0.5f * (tr + mah - 4.0f + q2.z - la);
        // sigmoid(-kl/tau)*chi; e->inf => rcp(inf)=0 (correct limit)
        const float e = __expf(kl * kInvTau);
        const float s = xchi * __builtin_amdgcn_rcpf(1.0f + e);
        out[(n * kM + m) * kGH + gh] = s;
    }
}

}  // namespace

extern "C" void kernel_launch(void* const* d_in, const int* in_sizes, int n_in,
                              void* d_out, int out_size, void* d_ws, size_t ws_size,
                              hipStream_t stream) {
    const float* mu_a    = (const float*)d_in[0];
    const float* sigma_a = (const float*)d_in[1];
    const float* omega_a = (const float*)d_in[2];
    const float* mu_b    = (const float*)d_in[3];
    const float* sigma_b = (const float*)d_in[4];
    const float* omega_b = (const float*)d_in[5];
    const float* chi     = (const float*)d_in[6];
    float* out = (float*)d_out;
    float4* ws = (float4*)d_ws;  // needs 4*32768*16 B = 2 MiB

    precompute_b_kernel<<<kMB / 256, 256, 0, stream>>>(mu_b, sigma_b, omega_b, ws);

    species_kernel<<<kNA / 256, 256, 0, stream>>>(
        mu_a, sigma_a, omega_a, chi, ws, out);
}